// Round 8
// baseline (431.276 us; speedup 1.0000x reference)
//
#include <hip/hip_runtime.h>
#include <hip/hip_bf16.h>

// VQ-VAE vector quantizer, MI355X. z:(16,512,64,64) f32, codebook:(1024,512) f32.
// d_out f32: z_q (33554432), loss (1), idx (65536).

typedef _Float16 h8 __attribute__((ext_vector_type(8)));
typedef float f32x16 __attribute__((ext_vector_type(16)));

#define OUT_LOSS  33554432
#define OUT_IDX   33554433
#define MARGIN_T  0.15f     // ~13 sigma of fp16-dot noise on the t-gap

__device__ __forceinline__ void gload_lds16(const void* g, void* l) {
  __builtin_amdgcn_global_load_lds(
      (const __attribute__((address_space(1))) void*)g,
      (__attribute__((address_space(3))) void*)l, 16, 0, 0);
}

// ---- K0: cb fp32->fp16, fold-ordered 0.5||c||^2 table, workspace init ---------
__global__ __launch_bounds__(64) void k0_prep(
    const float* __restrict__ cb, unsigned short* __restrict__ cb16,
    float* __restrict__ cnp, int* __restrict__ counters, float* __restrict__ loss_acc,
    int* __restrict__ idx_ws, unsigned long long* __restrict__ packed_ws)
{
  const int r = blockIdx.x, l = threadIdx.x;
  const float* row = cb + (size_t)r * 512;
  float4 a  = *(const float4*)(row + l * 8);
  float4 b4 = *(const float4*)(row + l * 8 + 4);
  h8 hv;
  hv[0] = (_Float16)a.x;  hv[1] = (_Float16)a.y;  hv[2] = (_Float16)a.z;  hv[3] = (_Float16)a.w;
  hv[4] = (_Float16)b4.x; hv[5] = (_Float16)b4.y; hv[6] = (_Float16)b4.z; hv[7] = (_Float16)b4.w;
  *reinterpret_cast<h8*>(cb16 + (size_t)r * 512 + l * 8) = hv;
  float s = a.x*a.x + a.y*a.y + a.z*a.z + a.w*a.w
          + b4.x*b4.x + b4.y*b4.y + b4.z*b4.z + b4.w*b4.w;
  #pragma unroll
  for (int off = 1; off < 64; off <<= 1) s += __shfl_xor(s, off);
  if (l == 0) {
    // store 0.5*||c||^2 at the fold-order slot: [ch][khalf][reg]
    int jr = r & 31, ch = r >> 5;
    int khalf = (jr >> 2) & 1;
    int pat = jr - (khalf << 2);
    int rr  = (pat & 3) + ((pat >> 3) << 2);
    cnp[(ch << 5) + (khalf << 4) + rr] = 0.5f * s;
  }
  const int pix = (r << 6) + l;                // 1024x64 == 65536
  idx_ws[pix] = (int)0x80000000;
  packed_ws[pix] = ~0ull;
  if (r == 0 && l == 0) { counters[0] = 0; counters[1] = 0; *loss_acc = 0.f; }
}

// ---- K1: fp16 MFMA scan — 64 stages, triple-buffer, counted vmcnt, setprio ----
// 512 blocks x 256 thr (4 waves), 128 px/block. dynLDS = 3*16384 + 4096 = 53248.
// Stage st = (chunk c = st>>1, K-half h = st&1): 32 codes x 256 channels (16KB).
// LDS layout per buffer: off = m*512 + row*16, m = 8-channel group (0..31).
// A-read (lane pxl,khalf; k-slot q): off = q*1024 + khalf*512 + pxl*16 -> the
// wave reads a contiguous 1KB per slot: conflict-free, imm-offset addressing.
__global__ __launch_bounds__(256, 2) void k1_main(
    const float* __restrict__ z, const unsigned short* __restrict__ cb16,
    const float* __restrict__ cnp,
    int* __restrict__ idx_ws, int* __restrict__ flaglist,
    unsigned long long* __restrict__ pairlist, int* __restrict__ counters)
{
  extern __shared__ char smem[];
  float* cn_lds = reinterpret_cast<float*>(smem + 49152);
  const int tid   = threadIdx.x;
  const int lane  = tid & 63;
  const int wave  = tid >> 6;          // 0..3
  const int pxl   = lane & 31;
  const int khalf = lane >> 5;
  const int px0   = blockIdx.x << 7;   // 128 px/block
  const int b     = px0 >> 12;
  const int hw0   = px0 & 4095;
  const char* cbB = reinterpret_cast<const char*>(cb16);
  // source swizzle so linear LDS dest receives the transposed layout:
  const int laneoff = pxl * 1024 + khalf * 16;

  // prologue: stage st=0 (c0,h0)->buf0 and st=1 (c0,h1)->buf1
  #pragma unroll
  for (int i = 0; i < 4; ++i)
    gload_lds16(cbB + laneoff + wave * 128 + i * 32,
                smem + wave * 4096 + i * 1024);
  #pragma unroll
  for (int i = 0; i < 4; ++i)
    gload_lds16(cbB + 512 + laneoff + wave * 128 + i * 32,
                smem + 16384 + wave * 4096 + i * 1024);

  // B-fragments straight from global: 32 px/wave x K=512 fp16 in VGPRs
  h8 bfrag[32];
  {
    const float* zl = z + ((size_t)(b * 512 + khalf * 8)) * 4096 + hw0 + (wave << 5) + pxl;
    #pragma unroll
    for (int s = 0; s < 32; ++s) {
      const float* zs = zl + (size_t)s * 16 * 4096;
      h8 hv;
      #pragma unroll
      for (int e = 0; e < 8; ++e) hv[e] = (_Float16)zs[(size_t)e * 4096];
      bfrag[s] = hv;
    }
  }
  for (int i = tid; i < 1024; i += 256) cn_lds[i] = cnp[i];
  __syncthreads();   // drains ALL vmem (incl. st0/st1 staging): counter = 0 here

  float v0 = INFINITY, v1 = INFINITY, v2 = INFINITY, v3 = INFINITY;
  int   i0 = 0, i1 = 0, i2 = 0, i3 = 0;
  f32x16 acc;
  #pragma unroll
  for (int i = 0; i < 16; ++i) acc[i] = 0.f;

  for (int st = 0; st < 64; ++st) {
    const int h = st & 1;
    const char* cbuf = smem + (st % 3) * 16384;
    // counted vmcnt: at stage top, outstanding = st's 4 (pre-drained for st<2)
    // + st+1's 4. Keep st+1's in flight; drain only our own.
    if (st < 63) { asm volatile("s_waitcnt vmcnt(4)" ::: "memory"); }
    else         { asm volatile("s_waitcnt vmcnt(0)" ::: "memory"); }
    __builtin_amdgcn_s_barrier();
    __builtin_amdgcn_sched_barrier(0);

    if (st + 2 < 64) {   // issue st+2's staging: hides under this stage's MFMA
      const int c2 = (st + 2) >> 1, h2 = (st + 2) & 1;
      char* dbuf = smem + ((st + 2) % 3) * 16384;
      const char* src = cbB + c2 * 32768 + h2 * 512 + laneoff + wave * 128;
      #pragma unroll
      for (int i = 0; i < 4; ++i)
        gload_lds16(src + i * 32, dbuf + wave * 4096 + i * 1024);
    }

    // 4 sub-phases: {4 ds_read_b128 ; 4 MFMA} — fine interleave, prio'd MFMA
    const char* ab = cbuf + (pxl << 4) + (khalf << 9);
    #pragma unroll
    for (int q = 0; q < 4; ++q) {
      h8 a0 = *reinterpret_cast<const h8*>(ab + ((q * 4 + 0) << 10));
      h8 a1 = *reinterpret_cast<const h8*>(ab + ((q * 4 + 1) << 10));
      h8 a2 = *reinterpret_cast<const h8*>(ab + ((q * 4 + 2) << 10));
      h8 a3 = *reinterpret_cast<const h8*>(ab + ((q * 4 + 3) << 10));
      __builtin_amdgcn_s_setprio(1);
      acc = __builtin_amdgcn_mfma_f32_32x32x16_f16(a0, bfrag[h * 16 + q * 4 + 0], acc, 0, 0, 0);
      acc = __builtin_amdgcn_mfma_f32_32x32x16_f16(a1, bfrag[h * 16 + q * 4 + 1], acc, 0, 0, 0);
      acc = __builtin_amdgcn_mfma_f32_32x32x16_f16(a2, bfrag[h * 16 + q * 4 + 2], acc, 0, 0, 0);
      acc = __builtin_amdgcn_mfma_f32_32x32x16_f16(a3, bfrag[h * 16 + q * 4 + 3], acc, 0, 0, 0);
      __builtin_amdgcn_s_setprio(0);
    }

    if (h) {   // fold chunk c = st>>1: scores, min-tree filter, rare insert
      const int c = st >> 1;
      const float* cl = cn_lds + (c << 5) + (khalf << 4);
      float4 q0 = *(const float4*)(cl);     float4 q1 = *(const float4*)(cl + 4);
      float4 q2 = *(const float4*)(cl + 8); float4 q3 = *(const float4*)(cl + 12);
      const float cn[16] = {q0.x,q0.y,q0.z,q0.w, q1.x,q1.y,q1.z,q1.w,
                            q2.x,q2.y,q2.z,q2.w, q3.x,q3.y,q3.z,q3.w};
      float sc[16];
      #pragma unroll
      for (int r = 0; r < 16; ++r) sc[r] = cn[r] - acc[r];   // 0.5||c||^2 - z.c
      float mn = sc[0];
      #pragma unroll
      for (int r = 1; r < 16; ++r) mn = fminf(mn, sc[r]);
      if (__ballot(mn < v3)) {   // wave-uniform skip; body branch-free
        const int jbase = (c << 5) + (khalf << 2);
        #pragma unroll
        for (int r = 0; r < 16; ++r) {
          int j = jbase + ((r & 3) + ((r >> 2) << 3));
          float s = sc[r];
          bool c0 = s < v0, c1 = s < v1, c2 = s < v2, c3 = s < v3;
          v3 = c2 ? v2 : (c3 ? s : v3);  i3 = c2 ? i2 : (c3 ? j : i3);
          v2 = c1 ? v1 : (c2 ? s : v2);  i2 = c1 ? i1 : (c2 ? j : i2);
          v1 = c0 ? v0 : (c1 ? s : v1);  i1 = c0 ? i0 : (c1 ? j : i1);
          v0 = c0 ? s  : v0;             i0 = c0 ? j  : i0;
        }
      }
      #pragma unroll
      for (int i = 0; i < 16; ++i) acc[i] = 0.f;
    }
  }

  // merge khalf halves: snapshot partner's full list BEFORE mutating ours
  {
    float ow0 = __shfl_xor(v0, 32), ow1 = __shfl_xor(v1, 32),
          ow2 = __shfl_xor(v2, 32), ow3 = __shfl_xor(v3, 32);
    int   oj0 = __shfl_xor(i0, 32), oj1 = __shfl_xor(i1, 32),
          oj2 = __shfl_xor(i2, 32), oj3 = __shfl_xor(i3, 32);
    const float ow[4] = {ow0, ow1, ow2, ow3};
    const int   oj[4] = {oj0, oj1, oj2, oj3};
    #pragma unroll
    for (int k = 0; k < 4; ++k) {
      float ov = ow[k]; int oi = oj[k];
      bool c0 = ov < v0, c1 = ov < v1, c2 = ov < v2, c3 = ov < v3;
      v3 = c2 ? v2 : (c3 ? ov : v3);  i3 = c2 ? i2 : (c3 ? oi : i3);
      v2 = c1 ? v1 : (c2 ? ov : v2);  i2 = c1 ? i1 : (c2 ? oi : i2);
      v1 = c0 ? v0 : (c1 ? ov : v1);  i1 = c0 ? i0 : (c1 ? oi : i1);
      v0 = c0 ? ov : v0;              i0 = c0 ? oi : i0;
    }
  }

  const int pix = px0 + (wave << 5) + lane;   // valid for lane<32 only
  bool sane = (v0 == v0) && (v3 == v3) && ((unsigned)i0 < 1024u);
  bool unfl = sane && (v1 - v0 >= MARGIN_T);
  bool quad = sane && !unfl && (v3 - v0 >= MARGIN_T);
  bool qpred = (lane < 32) && quad;
  bool fpred = (lane < 32) && !unfl && !quad;
  if (lane < 32) idx_ws[pix] = unfl ? i0 : (int)0x80000000;

  unsigned long long qm = __ballot(qpred);
  if (qm) {
    int leader = __ffsll(qm) - 1;
    int base = 0;
    if (lane == leader) base = atomicAdd(&counters[1], __popcll(qm));
    base = __shfl(base, leader);
    if (qpred) {
      int pos = __popcll(qm & ((1ull << lane) - 1ull));
      pairlist[base + pos] = (unsigned long long)(unsigned)pix
          | ((unsigned long long)(unsigned)i0 << 16)
          | ((unsigned long long)(unsigned)i1 << 26)
          | ((unsigned long long)(unsigned)i2 << 36)
          | ((unsigned long long)(unsigned)i3 << 46);
    }
  }
  unsigned long long fm = __ballot(fpred);
  if (fm) {
    int leader = __ffsll(fm) - 1;
    int base = 0;
    if (lane == leader) base = atomicAdd(&counters[0], __popcll(fm));
    base = __shfl(base, leader);
    if (fpred) {
      int pos = __popcll(fm & ((1ull << lane) - 1ull));
      flaglist[base + pos] = pix;
    }
  }
}

// ---- K2a: exact fp64 check of <=4 candidates, one wave per pixel --------------
__global__ __launch_bounds__(256) void k2a_quad(
    const float* __restrict__ z, const float* __restrict__ cb,
    const unsigned long long* __restrict__ pairlist, const int* __restrict__ counters,
    int* __restrict__ idx_ws)
{
  const int lane = threadIdx.x & 63;
  const int wid  = (blockIdx.x << 2) + (threadIdx.x >> 6);
  const int nwav = gridDim.x << 2;
  const int nf   = counters[1];
  for (int e = wid; e < nf; e += nwav) {
    unsigned long long pk = pairlist[e];
    int pix = (int)(pk & 0xFFFFull);
    int c0 = (int)((pk >> 16) & 1023ull), c1 = (int)((pk >> 26) & 1023ull);
    int c2 = (int)((pk >> 36) & 1023ull), c3 = (int)((pk >> 46) & 1023ull);
    const float* zp = z + (size_t)(pix >> 12) * 512 * 4096 + (pix & 4095);
    double s0 = 0, s1 = 0, s2 = 0, s3 = 0;
    #pragma unroll
    for (int k = 0; k < 8; ++k) {
      int c = lane + (k << 6);
      double zv2 = 2.0 * (double)zp[(size_t)c * 4096];
      double a;
      a = (double)cb[(size_t)c0 * 512 + c]; s0 = fma(a, a - zv2, s0);
      a = (double)cb[(size_t)c1 * 512 + c]; s1 = fma(a, a - zv2, s1);
      a = (double)cb[(size_t)c2 * 512 + c]; s2 = fma(a, a - zv2, s2);
      a = (double)cb[(size_t)c3 * 512 + c]; s3 = fma(a, a - zv2, s3);
    }
    #pragma unroll
    for (int off = 32; off > 0; off >>= 1) {
      s0 += __shfl_xor(s0, off); s1 += __shfl_xor(s1, off);
      s2 += __shfl_xor(s2, off); s3 += __shfl_xor(s3, off);
    }
    double bv = s0; int bi = c0;
    if (s1 < bv || (s1 == bv && c1 < bi)) { bv = s1; bi = c1; }
    if (s2 < bv || (s2 == bv && c2 < bi)) { bv = s2; bi = c2; }
    if (s3 < bv || (s3 == bv && c3 < bi)) { bv = s3; bi = c3; }
    if (lane == 0) idx_ws[pix] = bi;
  }
}

// ---- K2b: exact fp64 full re-rank (rare: >=4 codes within margin) -------------
__global__ __launch_bounds__(256) void k2_rescan(
    const float* __restrict__ z, const float* __restrict__ cb,
    const int* __restrict__ flaglist, const int* __restrict__ counters,
    unsigned long long* __restrict__ packed_ws)
{
  __shared__ float zb[16][512];
  __shared__ unsigned long long best[16];
  __shared__ int pixl[16];
  const int t = threadIdx.x;
  const int nflag = counters[0];
  const int ntasks = ((nflag + 15) >> 4) << 2;
  for (int task = blockIdx.x; task < ntasks; task += gridDim.x) {
    const int g = task >> 2, q = task & 3;
    int rem = nflag - (g << 4);
    const int npx = rem < 16 ? rem : 16;
    if (t < 16) {
      best[t] = ~0ull;
      pixl[t] = (t < npx) ? flaglist[(g << 4) + t] : 0;
    }
    __syncthreads();
    for (int i = t; i < (npx << 9); i += 256) {
      int p = i >> 9, c = i & 511;
      int pix = pixl[p];
      zb[p][c] = z[((size_t)(pix >> 12) * 512 + c) * 4096 + (pix & 4095)];
    }
    __syncthreads();
    const int j = (q << 8) + t;
    const float* row = cb + (size_t)j * 512;
    double dot[16];
    #pragma unroll
    for (int p = 0; p < 16; ++p) dot[p] = 0.0;
    double cn = 0.0;
    for (int k = 0; k < 512; k += 4) {
      float4 cv = *(const float4*)(row + k);
      double c0 = cv.x, c1 = cv.y, c2 = cv.z, c3 = cv.w;
      cn = fma(c0, c0, cn); cn = fma(c1, c1, cn);
      cn = fma(c2, c2, cn); cn = fma(c3, c3, cn);
      #pragma unroll
      for (int p = 0; p < 16; ++p) {
        dot[p] = fma(c0, (double)zb[p][k + 0], dot[p]);
        dot[p] = fma(c1, (double)zb[p][k + 1], dot[p]);
        dot[p] = fma(c2, (double)zb[p][k + 2], dot[p]);
        dot[p] = fma(c3, (double)zb[p][k + 3], dot[p]);
      }
    }
    #pragma unroll
    for (int p = 0; p < 16; ++p) {
      if (p < npx) {
        double d = fma(-2.0, dot[p], cn);
        unsigned long long u = (unsigned long long)__double_as_longlong(d);
        u = (u >> 63) ? ~u : (u | 0x8000000000000000ull);
        unsigned long long pkk = (u & ~1023ull) | (unsigned long long)j;
        atomicMin(&best[p], pkk);
      }
    }
    __syncthreads();
    if (t < npx) atomicMin(&packed_ws[pixl[t]], best[t]);
    __syncthreads();
  }
}

// ---- K3: gather + transpose-write z_q (f32), idx (f32), loss ------------------
__global__ __launch_bounds__(256) void k3_out(
    const float* __restrict__ z, const float* __restrict__ cb,
    const int* __restrict__ idx_ws, const unsigned long long* __restrict__ packed_ws,
    float* __restrict__ out, float* __restrict__ loss_acc)
{
  extern __shared__ float rows[];         // [32][513]
  __shared__ int idxs[32];
  __shared__ float wsum[4];
  const int t = threadIdx.x;
  const int pix0 = blockIdx.x << 5;       // 32 px/block
  const int b = pix0 >> 12, hw0 = pix0 & 4095;
  if (t < 32) {
    int pix = pix0 + t;
    int v = idx_ws[pix];
    unsigned j = (v < 0) ? (unsigned)(packed_ws[pix] & 1023ull) : (unsigned)v;
    j &= 1023u;
    idxs[t] = (int)j;
    out[OUT_IDX + pix] = (float)j;
  }
  __syncthreads();
  for (int i = t; i < 32 * 128; i += 256) {
    int r = i >> 7, kq = (i & 127) << 2;
    float4 v = *(const float4*)(cb + (size_t)idxs[r] * 512 + kq);
    float* dst = rows + r * 513 + kq;
    dst[0] = v.x; dst[1] = v.y; dst[2] = v.z; dst[3] = v.w;
  }
  __syncthreads();
  const int pl = (t & 7) << 2;   // pixel quad {0,4,...,28}
  const int cg = t >> 3;         // 0..31
  float acc = 0.f;
  for (int c0 = 0; c0 < 512; c0 += 32) {
    int c = c0 + cg;
    size_t go = ((size_t)(b * 512 + c)) * 4096 + hw0 + pl;
    float4 zv = *(const float4*)(z + go);
    float q0 = rows[(pl + 0) * 513 + c], q1 = rows[(pl + 1) * 513 + c];
    float q2 = rows[(pl + 2) * 513 + c], q3 = rows[(pl + 3) * 513 + c];
    float d0 = q0 - zv.x, d1 = q1 - zv.y, d2 = q2 - zv.z, d3 = q3 - zv.w;
    acc = fmaf(d0, d0, acc); acc = fmaf(d1, d1, acc);
    acc = fmaf(d2, d2, acc); acc = fmaf(d3, d3, acc);
    float4 qv;
    qv.x = zv.x + d0; qv.y = zv.y + d1;    // mimic ref: zp + (z_q - zp)
    qv.z = zv.z + d2; qv.w = zv.w + d3;
    *reinterpret_cast<float4*>(out + go) = qv;
  }
  #pragma unroll
  for (int off = 32; off > 0; off >>= 1) acc += __shfl_down(acc, off);
  if ((t & 63) == 0) wsum[t >> 6] = acc;
  __syncthreads();
  if (t == 0) atomicAdd(loss_acc, wsum[0] + wsum[1] + wsum[2] + wsum[3]);
}

__global__ void k4_loss(const float* __restrict__ loss_acc, float* __restrict__ out)
{
  if (threadIdx.x == 0 && blockIdx.x == 0)
    out[OUT_LOSS] = loss_acc[0] * (1.25f / 33554432.f);
}

// ---- launch --------------------------------------------------------------------
extern "C" void kernel_launch(void* const* d_in, const int* in_sizes, int n_in,
                              void* d_out, int out_size, void* d_ws, size_t ws_size,
                              hipStream_t stream) {
  const float* z  = (const float*)d_in[0];
  const float* cb = (const float*)d_in[1];
  float* out = (float*)d_out;
  char* ws = (char*)d_ws;
  unsigned short*      cb16      = (unsigned short*)(ws);                 // 1 MB
  float*               cnp       = (float*)(ws + 1048576);                // 4 KB
  int*                 idx_ws    = (int*)(ws + 1052672);                  // 256 KB
  unsigned long long*  packed_ws = (unsigned long long*)(ws + 1314816);   // 512 KB
  int*                 flaglist  = (int*)(ws + 1839104);                  // 256 KB
  unsigned long long*  pairlist  = (unsigned long long*)(ws + 2095360);   // 512 KB
  int*                 counters  = (int*)(ws + 2619648);                  // [flag, pair]
  float*               loss_acc  = (float*)(ws + 2619656);

  (void)hipFuncSetAttribute((const void*)k1_main,
        hipFuncAttributeMaxDynamicSharedMemorySize, 53248);
  (void)hipFuncSetAttribute((const void*)k3_out,
        hipFuncAttributeMaxDynamicSharedMemorySize, 65664);

  k0_prep<<<1024, 64, 0, stream>>>(cb, cb16, cnp, counters, loss_acc, idx_ws, packed_ws);
  k1_main<<<512, 256, 53248, stream>>>(z, cb16, cnp, idx_ws, flaglist, pairlist, counters);
  k2a_quad<<<1024, 256, 0, stream>>>(z, cb, pairlist, counters, idx_ws);
  k2_rescan<<<256, 256, 0, stream>>>(z, cb, flaglist, counters, packed_ws);
  k3_out<<<2048, 256, 65664, stream>>>(z, cb, idx_ws, packed_ws, out, loss_acc);
  k4_loss<<<1, 1, 0, stream>>>(loss_acc, out);
}

// Round 9
// 186.233 us; speedup vs baseline: 2.3158x; 2.3158x over previous
//
#include <hip/hip_runtime.h>
#include <hip/hip_bf16.h>

// VQ-VAE vector quantizer, MI355X. z:(16,512,64,64) f32, codebook:(1024,512) f32.
// d_out f32: z_q (33554432), loss (1), idx (65536).

typedef _Float16 h8 __attribute__((ext_vector_type(8)));
typedef float f32x16 __attribute__((ext_vector_type(16)));

#define OUT_LOSS  33554432
#define OUT_IDX   33554433
#define MARGIN_T  0.15f     // ~13 sigma of fp16-dot noise on the t-gap

__device__ __forceinline__ void gload_lds16(const void* g, void* l) {
  __builtin_amdgcn_global_load_lds(
      (const __attribute__((address_space(1))) void*)g,
      (__attribute__((address_space(3))) void*)l, 16, 0, 0);
}

// ---- K0: cb fp32->fp16, fold-ordered 0.5||c||^2 table, workspace init ---------
__global__ __launch_bounds__(64) void k0_prep(
    const float* __restrict__ cb, unsigned short* __restrict__ cb16,
    float* __restrict__ cnp, int* __restrict__ counters, float* __restrict__ loss_acc,
    int* __restrict__ idx_ws, unsigned long long* __restrict__ packed_ws)
{
  const int r = blockIdx.x, l = threadIdx.x;
  const float* row = cb + (size_t)r * 512;
  float4 a  = *(const float4*)(row + l * 8);
  float4 b4 = *(const float4*)(row + l * 8 + 4);
  h8 hv;
  hv[0] = (_Float16)a.x;  hv[1] = (_Float16)a.y;  hv[2] = (_Float16)a.z;  hv[3] = (_Float16)a.w;
  hv[4] = (_Float16)b4.x; hv[5] = (_Float16)b4.y; hv[6] = (_Float16)b4.z; hv[7] = (_Float16)b4.w;
  *reinterpret_cast<h8*>(cb16 + (size_t)r * 512 + l * 8) = hv;
  float s = a.x*a.x + a.y*a.y + a.z*a.z + a.w*a.w
          + b4.x*b4.x + b4.y*b4.y + b4.z*b4.z + b4.w*b4.w;
  #pragma unroll
  for (int off = 1; off < 64; off <<= 1) s += __shfl_xor(s, off);
  if (l == 0) {
    // store 0.5*||c||^2 at the fold-order slot: [ch][khalf][reg]
    int jr = r & 31, ch = r >> 5;
    int khalf = (jr >> 2) & 1;
    int pat = jr - (khalf << 2);
    int rr  = (pat & 3) + ((pat >> 3) << 2);
    cnp[(ch << 5) + (khalf << 4) + rr] = 0.5f * s;
  }
  const int pix = (r << 6) + l;                // 1024x64 == 65536
  idx_ws[pix] = (int)0x80000000;
  packed_ws[pix] = ~0ull;
  if (r == 0 && l == 0) { counters[0] = 0; counters[1] = 0; *loss_acc = 0.f; }
}

// ---- K1: fp16 MFMA scan — 64 stages (32 chunks x 2 static halves), ------------
//      triple-buffer via pointer rotation, counted vmcnt, setprio.
// 512 blocks x 256 thr (4 waves), 128 px/block. dynLDS = 3*16384 + 4096 = 53248.
// All bfrag[] indices are COMPILE-TIME (rule #20: runtime-indexed ext_vector
// arrays spill to scratch — that was R8's 1.1 GB FETCH / 416 us regression).
__global__ __launch_bounds__(256, 2) void k1_main(
    const float* __restrict__ z, const unsigned short* __restrict__ cb16,
    const float* __restrict__ cnp,
    int* __restrict__ idx_ws, int* __restrict__ flaglist,
    unsigned long long* __restrict__ pairlist, int* __restrict__ counters)
{
  extern __shared__ char smem[];
  float* cn_lds = reinterpret_cast<float*>(smem + 49152);
  const int tid   = threadIdx.x;
  const int lane  = tid & 63;
  const int wave  = tid >> 6;          // 0..3
  const int pxl   = lane & 31;
  const int khalf = lane >> 5;
  const int px0   = blockIdx.x << 7;   // 128 px/block
  const int b     = px0 >> 12;
  const int hw0   = px0 & 4095;
  const char* cbB = reinterpret_cast<const char*>(cb16);
  const int laneoff = pxl * 1024 + khalf * 16;   // source swizzle for linear LDS dest

  // prologue: stage st=0 (c0,h0)->buf0 and st=1 (c0,h1)->buf1
  #pragma unroll
  for (int i = 0; i < 4; ++i)
    gload_lds16(cbB + laneoff + wave * 128 + i * 32,
                smem + wave * 4096 + i * 1024);
  #pragma unroll
  for (int i = 0; i < 4; ++i)
    gload_lds16(cbB + 512 + laneoff + wave * 128 + i * 32,
                smem + 16384 + wave * 4096 + i * 1024);

  // B-fragments straight from global: 32 px/wave x K=512 fp16 in VGPRs
  h8 bfrag[32];
  {
    const float* zl = z + ((size_t)(b * 512 + khalf * 8)) * 4096 + hw0 + (wave << 5) + pxl;
    #pragma unroll
    for (int s = 0; s < 32; ++s) {
      const float* zs = zl + (size_t)s * 16 * 4096;
      h8 hv;
      #pragma unroll
      for (int e = 0; e < 8; ++e) hv[e] = (_Float16)zs[(size_t)e * 4096];
      bfrag[s] = hv;
    }
  }
  for (int i = tid; i < 1024; i += 256) cn_lds[i] = cnp[i];
  __syncthreads();   // drains ALL vmem (incl. st0/st1 staging): vmcnt = 0 here

  float v0 = INFINITY, v1 = INFINITY, v2 = INFINITY, v3 = INFINITY;
  int   i0 = 0, i1 = 0, i2 = 0, i3 = 0;
  f32x16 acc;
  #pragma unroll
  for (int i = 0; i < 16; ++i) acc[i] = 0.f;

  char* p0 = smem;            // buffer for stage 2c   (h=0)
  char* p1 = smem + 16384;    // buffer for stage 2c+1 (h=1)
  char* p2 = smem + 32768;    // buffer being staged for stage 2c+2

  for (int c = 0; c < 32; ++c) {
    const bool pf = (c < 31);

    // ---------- stage 2c (h=0): compute from p0; stage (c+1,h=0) -> p2 --------
    asm volatile("s_waitcnt vmcnt(4)" ::: "memory");   // stage 2c's loads landed
    __builtin_amdgcn_s_barrier();
    __builtin_amdgcn_sched_barrier(0);
    if (pf) {
      const char* src = cbB + (c + 1) * 32768 + laneoff + wave * 128;
      #pragma unroll
      for (int i = 0; i < 4; ++i)
        gload_lds16(src + i * 32, p2 + wave * 4096 + i * 1024);
    }
    {
      const char* ab = p0 + (pxl << 4) + (khalf << 9);
      #pragma unroll
      for (int q = 0; q < 4; ++q) {
        h8 a0 = *reinterpret_cast<const h8*>(ab + ((q * 4 + 0) << 10));
        h8 a1 = *reinterpret_cast<const h8*>(ab + ((q * 4 + 1) << 10));
        h8 a2 = *reinterpret_cast<const h8*>(ab + ((q * 4 + 2) << 10));
        h8 a3 = *reinterpret_cast<const h8*>(ab + ((q * 4 + 3) << 10));
        __builtin_amdgcn_s_setprio(1);
        acc = __builtin_amdgcn_mfma_f32_32x32x16_f16(a0, bfrag[q * 4 + 0], acc, 0, 0, 0);
        acc = __builtin_amdgcn_mfma_f32_32x32x16_f16(a1, bfrag[q * 4 + 1], acc, 0, 0, 0);
        acc = __builtin_amdgcn_mfma_f32_32x32x16_f16(a2, bfrag[q * 4 + 2], acc, 0, 0, 0);
        acc = __builtin_amdgcn_mfma_f32_32x32x16_f16(a3, bfrag[q * 4 + 3], acc, 0, 0, 0);
        __builtin_amdgcn_s_setprio(0);
      }
    }

    // ---------- stage 2c+1 (h=1): compute from p1; stage (c+1,h=1) -> p0 ------
    if (pf) { asm volatile("s_waitcnt vmcnt(4)" ::: "memory"); }
    else    { asm volatile("s_waitcnt vmcnt(0)" ::: "memory"); }
    __builtin_amdgcn_s_barrier();
    __builtin_amdgcn_sched_barrier(0);
    if (pf) {
      const char* src = cbB + (c + 1) * 32768 + 512 + laneoff + wave * 128;
      #pragma unroll
      for (int i = 0; i < 4; ++i)
        gload_lds16(src + i * 32, p0 + wave * 4096 + i * 1024);
    }
    {
      const char* ab = p1 + (pxl << 4) + (khalf << 9);
      #pragma unroll
      for (int q = 0; q < 4; ++q) {
        h8 a0 = *reinterpret_cast<const h8*>(ab + ((q * 4 + 0) << 10));
        h8 a1 = *reinterpret_cast<const h8*>(ab + ((q * 4 + 1) << 10));
        h8 a2 = *reinterpret_cast<const h8*>(ab + ((q * 4 + 2) << 10));
        h8 a3 = *reinterpret_cast<const h8*>(ab + ((q * 4 + 3) << 10));
        __builtin_amdgcn_s_setprio(1);
        acc = __builtin_amdgcn_mfma_f32_32x32x16_f16(a0, bfrag[16 + q * 4 + 0], acc, 0, 0, 0);
        acc = __builtin_amdgcn_mfma_f32_32x32x16_f16(a1, bfrag[16 + q * 4 + 1], acc, 0, 0, 0);
        acc = __builtin_amdgcn_mfma_f32_32x32x16_f16(a2, bfrag[16 + q * 4 + 2], acc, 0, 0, 0);
        acc = __builtin_amdgcn_mfma_f32_32x32x16_f16(a3, bfrag[16 + q * 4 + 3], acc, 0, 0, 0);
        __builtin_amdgcn_s_setprio(0);
      }
    }

    // ---------- fold chunk c: scores, min-tree filter, rare branch-free insert -
    {
      const float* cl = cn_lds + (c << 5) + (khalf << 4);
      float4 q0 = *(const float4*)(cl);     float4 q1 = *(const float4*)(cl + 4);
      float4 q2 = *(const float4*)(cl + 8); float4 q3 = *(const float4*)(cl + 12);
      const float cn[16] = {q0.x,q0.y,q0.z,q0.w, q1.x,q1.y,q1.z,q1.w,
                            q2.x,q2.y,q2.z,q2.w, q3.x,q3.y,q3.z,q3.w};
      float sc[16];
      #pragma unroll
      for (int r = 0; r < 16; ++r) sc[r] = cn[r] - acc[r];   // 0.5||c||^2 - z.c
      float mn = sc[0];
      #pragma unroll
      for (int r = 1; r < 16; ++r) mn = fminf(mn, sc[r]);
      if (__ballot(mn < v3)) {   // wave-uniform skip; body branch-free
        const int jbase = (c << 5) + (khalf << 2);
        #pragma unroll
        for (int r = 0; r < 16; ++r) {
          int j = jbase + ((r & 3) + ((r >> 2) << 3));
          float s = sc[r];
          bool c0 = s < v0, c1 = s < v1, c2 = s < v2, c3 = s < v3;
          v3 = c2 ? v2 : (c3 ? s : v3);  i3 = c2 ? i2 : (c3 ? j : i3);
          v2 = c1 ? v1 : (c2 ? s : v2);  i2 = c1 ? i1 : (c2 ? j : i2);
          v1 = c0 ? v0 : (c1 ? s : v1);  i1 = c0 ? i0 : (c1 ? j : i1);
          v0 = c0 ? s  : v0;             i0 = c0 ? j  : i0;
        }
      }
      #pragma unroll
      for (int i = 0; i < 16; ++i) acc[i] = 0.f;
    }

    // rotate buffers: (p0,p1,p2) <- (p2,p0,p1)
    char* t0 = p0; char* t1 = p1;
    p0 = p2; p1 = t0; p2 = t1;
  }

  // merge khalf halves: snapshot partner's full list BEFORE mutating ours
  {
    float ow0 = __shfl_xor(v0, 32), ow1 = __shfl_xor(v1, 32),
          ow2 = __shfl_xor(v2, 32), ow3 = __shfl_xor(v3, 32);
    int   oj0 = __shfl_xor(i0, 32), oj1 = __shfl_xor(i1, 32),
          oj2 = __shfl_xor(i2, 32), oj3 = __shfl_xor(i3, 32);
    const float ow[4] = {ow0, ow1, ow2, ow3};
    const int   oj[4] = {oj0, oj1, oj2, oj3};
    #pragma unroll
    for (int k = 0; k < 4; ++k) {
      float ov = ow[k]; int oi = oj[k];
      bool c0 = ov < v0, c1 = ov < v1, c2 = ov < v2, c3 = ov < v3;
      v3 = c2 ? v2 : (c3 ? ov : v3);  i3 = c2 ? i2 : (c3 ? oi : i3);
      v2 = c1 ? v1 : (c2 ? ov : v2);  i2 = c1 ? i1 : (c2 ? oi : i2);
      v1 = c0 ? v0 : (c1 ? ov : v1);  i1 = c0 ? i0 : (c1 ? oi : i1);
      v0 = c0 ? ov : v0;              i0 = c0 ? oi : i0;
    }
  }

  const int pix = px0 + (wave << 5) + lane;   // valid for lane<32 only
  bool sane = (v0 == v0) && (v3 == v3) && ((unsigned)i0 < 1024u);
  bool unfl = sane && (v1 - v0 >= MARGIN_T);
  bool quad = sane && !unfl && (v3 - v0 >= MARGIN_T);
  bool qpred = (lane < 32) && quad;
  bool fpred = (lane < 32) && !unfl && !quad;
  if (lane < 32) idx_ws[pix] = unfl ? i0 : (int)0x80000000;

  unsigned long long qm = __ballot(qpred);
  if (qm) {
    int leader = __ffsll(qm) - 1;
    int base = 0;
    if (lane == leader) base = atomicAdd(&counters[1], __popcll(qm));
    base = __shfl(base, leader);
    if (qpred) {
      int pos = __popcll(qm & ((1ull << lane) - 1ull));
      pairlist[base + pos] = (unsigned long long)(unsigned)pix
          | ((unsigned long long)(unsigned)i0 << 16)
          | ((unsigned long long)(unsigned)i1 << 26)
          | ((unsigned long long)(unsigned)i2 << 36)
          | ((unsigned long long)(unsigned)i3 << 46);
    }
  }
  unsigned long long fm = __ballot(fpred);
  if (fm) {
    int leader = __ffsll(fm) - 1;
    int base = 0;
    if (lane == leader) base = atomicAdd(&counters[0], __popcll(fm));
    base = __shfl(base, leader);
    if (fpred) {
      int pos = __popcll(fm & ((1ull << lane) - 1ull));
      flaglist[base + pos] = pix;
    }
  }
}

// ---- K2a: exact fp64 check of <=4 candidates, one wave per pixel --------------
__global__ __launch_bounds__(256) void k2a_quad(
    const float* __restrict__ z, const float* __restrict__ cb,
    const unsigned long long* __restrict__ pairlist, const int* __restrict__ counters,
    int* __restrict__ idx_ws)
{
  const int lane = threadIdx.x & 63;
  const int wid  = (blockIdx.x << 2) + (threadIdx.x >> 6);
  const int nwav = gridDim.x << 2;
  const int nf   = counters[1];
  for (int e = wid; e < nf; e += nwav) {
    unsigned long long pk = pairlist[e];
    int pix = (int)(pk & 0xFFFFull);
    int c0 = (int)((pk >> 16) & 1023ull), c1 = (int)((pk >> 26) & 1023ull);
    int c2 = (int)((pk >> 36) & 1023ull), c3 = (int)((pk >> 46) & 1023ull);
    const float* zp = z + (size_t)(pix >> 12) * 512 * 4096 + (pix & 4095);
    double s0 = 0, s1 = 0, s2 = 0, s3 = 0;
    #pragma unroll
    for (int k = 0; k < 8; ++k) {
      int c = lane + (k << 6);
      double zv2 = 2.0 * (double)zp[(size_t)c * 4096];
      double a;
      a = (double)cb[(size_t)c0 * 512 + c]; s0 = fma(a, a - zv2, s0);
      a = (double)cb[(size_t)c1 * 512 + c]; s1 = fma(a, a - zv2, s1);
      a = (double)cb[(size_t)c2 * 512 + c]; s2 = fma(a, a - zv2, s2);
      a = (double)cb[(size_t)c3 * 512 + c]; s3 = fma(a, a - zv2, s3);
    }
    #pragma unroll
    for (int off = 32; off > 0; off >>= 1) {
      s0 += __shfl_xor(s0, off); s1 += __shfl_xor(s1, off);
      s2 += __shfl_xor(s2, off); s3 += __shfl_xor(s3, off);
    }
    double bv = s0; int bi = c0;
    if (s1 < bv || (s1 == bv && c1 < bi)) { bv = s1; bi = c1; }
    if (s2 < bv || (s2 == bv && c2 < bi)) { bv = s2; bi = c2; }
    if (s3 < bv || (s3 == bv && c3 < bi)) { bv = s3; bi = c3; }
    if (lane == 0) idx_ws[pix] = bi;
  }
}

// ---- K2b: exact fp64 full re-rank (rare: >=4 codes within margin) -------------
__global__ __launch_bounds__(256) void k2_rescan(
    const float* __restrict__ z, const float* __restrict__ cb,
    const int* __restrict__ flaglist, const int* __restrict__ counters,
    unsigned long long* __restrict__ packed_ws)
{
  __shared__ float zb[16][512];
  __shared__ unsigned long long best[16];
  __shared__ int pixl[16];
  const int t = threadIdx.x;
  const int nflag = counters[0];
  const int ntasks = ((nflag + 15) >> 4) << 2;
  for (int task = blockIdx.x; task < ntasks; task += gridDim.x) {
    const int g = task >> 2, q = task & 3;
    int rem = nflag - (g << 4);
    const int npx = rem < 16 ? rem : 16;
    if (t < 16) {
      best[t] = ~0ull;
      pixl[t] = (t < npx) ? flaglist[(g << 4) + t] : 0;
    }
    __syncthreads();
    for (int i = t; i < (npx << 9); i += 256) {
      int p = i >> 9, c = i & 511;
      int pix = pixl[p];
      zb[p][c] = z[((size_t)(pix >> 12) * 512 + c) * 4096 + (pix & 4095)];
    }
    __syncthreads();
    const int j = (q << 8) + t;
    const float* row = cb + (size_t)j * 512;
    double dot[16];
    #pragma unroll
    for (int p = 0; p < 16; ++p) dot[p] = 0.0;
    double cn = 0.0;
    for (int k = 0; k < 512; k += 4) {
      float4 cv = *(const float4*)(row + k);
      double c0 = cv.x, c1 = cv.y, c2 = cv.z, c3 = cv.w;
      cn = fma(c0, c0, cn); cn = fma(c1, c1, cn);
      cn = fma(c2, c2, cn); cn = fma(c3, c3, cn);
      #pragma unroll
      for (int p = 0; p < 16; ++p) {
        dot[p] = fma(c0, (double)zb[p][k + 0], dot[p]);
        dot[p] = fma(c1, (double)zb[p][k + 1], dot[p]);
        dot[p] = fma(c2, (double)zb[p][k + 2], dot[p]);
        dot[p] = fma(c3, (double)zb[p][k + 3], dot[p]);
      }
    }
    #pragma unroll
    for (int p = 0; p < 16; ++p) {
      if (p < npx) {
        double d = fma(-2.0, dot[p], cn);
        unsigned long long u = (unsigned long long)__double_as_longlong(d);
        u = (u >> 63) ? ~u : (u | 0x8000000000000000ull);
        unsigned long long pkk = (u & ~1023ull) | (unsigned long long)j;
        atomicMin(&best[p], pkk);
      }
    }
    __syncthreads();
    if (t < npx) atomicMin(&packed_ws[pixl[t]], best[t]);
    __syncthreads();
  }
}

// ---- K3: gather + transpose-write z_q (f32), idx (f32), loss ------------------
__global__ __launch_bounds__(256) void k3_out(
    const float* __restrict__ z, const float* __restrict__ cb,
    const int* __restrict__ idx_ws, const unsigned long long* __restrict__ packed_ws,
    float* __restrict__ out, float* __restrict__ loss_acc)
{
  extern __shared__ float rows[];         // [32][513]
  __shared__ int idxs[32];
  __shared__ float wsum[4];
  const int t = threadIdx.x;
  const int pix0 = blockIdx.x << 5;       // 32 px/block
  const int b = pix0 >> 12, hw0 = pix0 & 4095;
  if (t < 32) {
    int pix = pix0 + t;
    int v = idx_ws[pix];
    unsigned j = (v < 0) ? (unsigned)(packed_ws[pix] & 1023ull) : (unsigned)v;
    j &= 1023u;
    idxs[t] = (int)j;
    out[OUT_IDX + pix] = (float)j;
  }
  __syncthreads();
  for (int i = t; i < 32 * 128; i += 256) {
    int r = i >> 7, kq = (i & 127) << 2;
    float4 v = *(const float4*)(cb + (size_t)idxs[r] * 512 + kq);
    float* dst = rows + r * 513 + kq;
    dst[0] = v.x; dst[1] = v.y; dst[2] = v.z; dst[3] = v.w;
  }
  __syncthreads();
  const int pl = (t & 7) << 2;   // pixel quad {0,4,...,28}
  const int cg = t >> 3;         // 0..31
  float acc = 0.f;
  for (int c0 = 0; c0 < 512; c0 += 32) {
    int c = c0 + cg;
    size_t go = ((size_t)(b * 512 + c)) * 4096 + hw0 + pl;
    float4 zv = *(const float4*)(z + go);
    float q0 = rows[(pl + 0) * 513 + c], q1 = rows[(pl + 1) * 513 + c];
    float q2 = rows[(pl + 2) * 513 + c], q3 = rows[(pl + 3) * 513 + c];
    float d0 = q0 - zv.x, d1 = q1 - zv.y, d2 = q2 - zv.z, d3 = q3 - zv.w;
    acc = fmaf(d0, d0, acc); acc = fmaf(d1, d1, acc);
    acc = fmaf(d2, d2, acc); acc = fmaf(d3, d3, acc);
    float4 qv;
    qv.x = zv.x + d0; qv.y = zv.y + d1;    // mimic ref: zp + (z_q - zp)
    qv.z = zv.z + d2; qv.w = zv.w + d3;
    *reinterpret_cast<float4*>(out + go) = qv;
  }
  #pragma unroll
  for (int off = 32; off > 0; off >>= 1) acc += __shfl_down(acc, off);
  if ((t & 63) == 0) wsum[t >> 6] = acc;
  __syncthreads();
  if (t == 0) atomicAdd(loss_acc, wsum[0] + wsum[1] + wsum[2] + wsum[3]);
}

__global__ void k4_loss(const float* __restrict__ loss_acc, float* __restrict__ out)
{
  if (threadIdx.x == 0 && blockIdx.x == 0)
    out[OUT_LOSS] = loss_acc[0] * (1.25f / 33554432.f);
}

// ---- launch --------------------------------------------------------------------
extern "C" void kernel_launch(void* const* d_in, const int* in_sizes, int n_in,
                              void* d_out, int out_size, void* d_ws, size_t ws_size,
                              hipStream_t stream) {
  const float* z  = (const float*)d_in[0];
  const float* cb = (const float*)d_in[1];
  float* out = (float*)d_out;
  char* ws = (char*)d_ws;
  unsigned short*      cb16      = (unsigned short*)(ws);                 // 1 MB
  float*               cnp       = (float*)(ws + 1048576);                // 4 KB
  int*                 idx_ws    = (int*)(ws + 1052672);                  // 256 KB
  unsigned long long*  packed_ws = (unsigned long long*)(ws + 1314816);   // 512 KB
  int*                 flaglist  = (int*)(ws + 1839104);                  // 256 KB
  unsigned long long*  pairlist  = (unsigned long long*)(ws + 2095360);   // 512 KB
  int*                 counters  = (int*)(ws + 2619648);                  // [flag, pair]
  float*               loss_acc  = (float*)(ws + 2619656);

  (void)hipFuncSetAttribute((const void*)k1_main,
        hipFuncAttributeMaxDynamicSharedMemorySize, 53248);
  (void)hipFuncSetAttribute((const void*)k3_out,
        hipFuncAttributeMaxDynamicSharedMemorySize, 65664);

  k0_prep<<<1024, 64, 0, stream>>>(cb, cb16, cnp, counters, loss_acc, idx_ws, packed_ws);
  k1_main<<<512, 256, 53248, stream>>>(z, cb16, cnp, idx_ws, flaglist, pairlist, counters);
  k2a_quad<<<1024, 256, 0, stream>>>(z, cb, pairlist, counters, idx_ws);
  k2_rescan<<<256, 256, 0, stream>>>(z, cb, flaglist, counters, packed_ws);
  k3_out<<<2048, 256, 65664, stream>>>(z, cb, idx_ws, packed_ws, out, loss_acc);
  k4_loss<<<1, 1, 0, stream>>>(loss_acc, out);
}

// Round 10
// 184.448 us; speedup vs baseline: 2.3382x; 1.0097x over previous
//
#include <hip/hip_runtime.h>
#include <hip/hip_bf16.h>

// VQ-VAE vector quantizer, MI355X. z:(16,512,64,64) f32, codebook:(1024,512) f32.
// d_out f32: z_q (33554432), loss (1), idx (65536).

typedef _Float16 h8 __attribute__((ext_vector_type(8)));
typedef float f32x16 __attribute__((ext_vector_type(16)));

#define OUT_LOSS  33554432
#define OUT_IDX   33554433
#define MARGIN_T  0.15f     // ~13 sigma of fp16-dot noise on the t-gap

// ---- K0: cb fp32 -> fp16 FRAGMENT-STREAM layout + 0.5||c||^2 + ws init --------
// cbT byte (c*32+s)*1024 + l*16 = code row (c*32 + (l&31)),
// channels [s*16 + (l>>5)*8, +8) as h8. A wave's A-fragment for (chunk c,
// k-slot s) is ONE contiguous, coalesced 1KB line.
__global__ __launch_bounds__(64) void k0_prep(
    const float* __restrict__ cb, unsigned short* __restrict__ cbT,
    float* __restrict__ cnp, int* __restrict__ counters, float* __restrict__ loss_acc,
    int* __restrict__ idx_ws, unsigned long long* __restrict__ packed_ws)
{
  const int r = blockIdx.x, l = threadIdx.x;   // r: code row, l: 8-channel group
  const float* row = cb + (size_t)r * 512;
  float4 a  = *(const float4*)(row + l * 8);
  float4 b4 = *(const float4*)(row + l * 8 + 4);
  h8 hv;
  hv[0] = (_Float16)a.x;  hv[1] = (_Float16)a.y;  hv[2] = (_Float16)a.z;  hv[3] = (_Float16)a.w;
  hv[4] = (_Float16)b4.x; hv[5] = (_Float16)b4.y; hv[6] = (_Float16)b4.z; hv[7] = (_Float16)b4.w;
  {
    const int c  = r >> 5, rr = r & 31;
    const int s  = l >> 1;                    // k-slot (16 channels)
    const int hk = l & 1;                     // k-half within slot
    char* dst = reinterpret_cast<char*>(cbT)
              + (size_t)c * 32768 + s * 1024 + (hk * 32 + rr) * 16;
    *reinterpret_cast<h8*>(dst) = hv;
  }
  float s = a.x*a.x + a.y*a.y + a.z*a.z + a.w*a.w
          + b4.x*b4.x + b4.y*b4.y + b4.z*b4.z + b4.w*b4.w;
  #pragma unroll
  for (int off = 1; off < 64; off <<= 1) s += __shfl_xor(s, off);
  if (l == 0) {
    // 0.5*||c||^2 at the fold-order slot: [c][khalf][reg]
    int jr = r & 31, c = r >> 5;
    int khalf = (jr >> 2) & 1;
    int pat = jr - (khalf << 2);
    int rr2 = (pat & 3) + ((pat >> 3) << 2);
    cnp[(c << 5) + (khalf << 4) + rr2] = 0.5f * s;
  }
  const int pix = (r << 6) + l;                // 1024x64 == 65536
  idx_ws[pix] = (int)0x80000000;
  packed_ws[pix] = ~0ull;
  if (r == 0 && l == 0) { counters[0] = 0; counters[1] = 0; *loss_acc = 0.f; }
}

// ---- K1: zero-LDS zero-barrier streaming MFMA scan + top-4 --------------------
// 512 blocks x 256 thr (4 independent waves), 32 px/wave. No __shared__.
// A-fragments stream from cbT via coalesced dwordx4 through a static ring of 8.
__global__ __launch_bounds__(256, 2) void k1_main(
    const float* __restrict__ z, const unsigned short* __restrict__ cbT,
    const float* __restrict__ cnp,
    int* __restrict__ idx_ws, int* __restrict__ flaglist,
    unsigned long long* __restrict__ pairlist, int* __restrict__ counters)
{
  const int tid   = threadIdx.x;
  const int lane  = tid & 63;
  const int wave  = tid >> 6;          // 0..3
  const int pxl   = lane & 31;
  const int khalf = lane >> 5;
  const int px0   = blockIdx.x << 7;   // 128 px/block
  const int b     = px0 >> 12;
  const int hw0   = px0 & 4095;

  // B-fragments straight from global: 32 px/wave x K=512 fp16 in VGPRs
  h8 bfrag[32];
  {
    const float* zl = z + ((size_t)(b * 512 + khalf * 8)) * 4096 + hw0 + (wave << 5) + pxl;
    #pragma unroll
    for (int s = 0; s < 32; ++s) {
      const float* zs = zl + (size_t)s * 16 * 4096;
      h8 hv;
      #pragma unroll
      for (int e = 0; e < 8; ++e) hv[e] = (_Float16)zs[(size_t)e * 4096];
      bfrag[s] = hv;
    }
  }

  float v0 = INFINITY, v1 = INFINITY, v2 = INFINITY, v3 = INFINITY;
  int   i0 = 0, i1 = 0, i2 = 0, i3 = 0;

  const char* gp = reinterpret_cast<const char*>(cbT) + lane * 16;  // stream base
  h8 ar[8];                                   // static ring (rule #20: indices static)
  #pragma unroll
  for (int s = 0; s < 8; ++s)
    ar[s] = *reinterpret_cast<const h8*>(gp + (s << 10));

  for (int c = 0; c < 32; ++c) {
    f32x16 acca, accb;
    #pragma unroll
    for (int i = 0; i < 16; ++i) { acca[i] = 0.f; accb[i] = 0.f; }

    #pragma unroll
    for (int s = 0; s < 32; ++s) {
      h8 a = ar[s & 7];
      if (s & 1) accb = __builtin_amdgcn_mfma_f32_32x32x16_f16(a, bfrag[s], accb, 0, 0, 0);
      else       acca = __builtin_amdgcn_mfma_f32_32x32x16_f16(a, bfrag[s], acca, 0, 0, 0);
      // refill ring with (c, s+8) — reads past c=31 stay in the 8KB slack
      ar[s & 7] = *reinterpret_cast<const h8*>(gp + ((s + 8) << 10));
    }
    gp += 32768;

    // fold chunk c: scores, min-tree filter, rare branch-free insert
    const float* cl = cnp + (c << 5) + (khalf << 4);
    float4 q0 = *(const float4*)(cl);     float4 q1 = *(const float4*)(cl + 4);
    float4 q2 = *(const float4*)(cl + 8); float4 q3 = *(const float4*)(cl + 12);
    const float cn[16] = {q0.x,q0.y,q0.z,q0.w, q1.x,q1.y,q1.z,q1.w,
                          q2.x,q2.y,q2.z,q2.w, q3.x,q3.y,q3.z,q3.w};
    float sc[16];
    #pragma unroll
    for (int r = 0; r < 16; ++r) sc[r] = cn[r] - (acca[r] + accb[r]);  // 0.5||c||^2 - z.c
    float mn = sc[0];
    #pragma unroll
    for (int r = 1; r < 16; ++r) mn = fminf(mn, sc[r]);
    if (__ballot(mn < v3)) {
      const int jbase = (c << 5) + (khalf << 2);
      #pragma unroll
      for (int r = 0; r < 16; ++r) {
        int j = jbase + ((r & 3) + ((r >> 2) << 3));
        float s = sc[r];
        bool c0 = s < v0, c1 = s < v1, c2 = s < v2, c3 = s < v3;
        v3 = c2 ? v2 : (c3 ? s : v3);  i3 = c2 ? i2 : (c3 ? j : i3);
        v2 = c1 ? v1 : (c2 ? s : v2);  i2 = c1 ? i1 : (c2 ? j : i2);
        v1 = c0 ? v0 : (c1 ? s : v1);  i1 = c0 ? i0 : (c1 ? j : i1);
        v0 = c0 ? s  : v0;             i0 = c0 ? j  : i0;
      }
    }
  }

  // merge khalf halves: snapshot partner's full list BEFORE mutating ours
  {
    float ow0 = __shfl_xor(v0, 32), ow1 = __shfl_xor(v1, 32),
          ow2 = __shfl_xor(v2, 32), ow3 = __shfl_xor(v3, 32);
    int   oj0 = __shfl_xor(i0, 32), oj1 = __shfl_xor(i1, 32),
          oj2 = __shfl_xor(i2, 32), oj3 = __shfl_xor(i3, 32);
    const float ow[4] = {ow0, ow1, ow2, ow3};
    const int   oj[4] = {oj0, oj1, oj2, oj3};
    #pragma unroll
    for (int k = 0; k < 4; ++k) {
      float ov = ow[k]; int oi = oj[k];
      bool c0 = ov < v0, c1 = ov < v1, c2 = ov < v2, c3 = ov < v3;
      v3 = c2 ? v2 : (c3 ? ov : v3);  i3 = c2 ? i2 : (c3 ? oi : i3);
      v2 = c1 ? v1 : (c2 ? ov : v2);  i2 = c1 ? i1 : (c2 ? oi : i2);
      v1 = c0 ? v0 : (c1 ? ov : v1);  i1 = c0 ? i0 : (c1 ? oi : i1);
      v0 = c0 ? ov : v0;              i0 = c0 ? oi : i0;
    }
  }

  const int pix = px0 + (wave << 5) + lane;   // valid for lane<32 only
  bool sane = (v0 == v0) && (v3 == v3) && ((unsigned)i0 < 1024u);
  bool unfl = sane && (v1 - v0 >= MARGIN_T);
  bool quad = sane && !unfl && (v3 - v0 >= MARGIN_T);
  bool qpred = (lane < 32) && quad;
  bool fpred = (lane < 32) && !unfl && !quad;
  if (lane < 32) idx_ws[pix] = unfl ? i0 : (int)0x80000000;

  unsigned long long qm = __ballot(qpred);
  if (qm) {
    int leader = __ffsll(qm) - 1;
    int base = 0;
    if (lane == leader) base = atomicAdd(&counters[1], __popcll(qm));
    base = __shfl(base, leader);
    if (qpred) {
      int pos = __popcll(qm & ((1ull << lane) - 1ull));
      pairlist[base + pos] = (unsigned long long)(unsigned)pix
          | ((unsigned long long)(unsigned)i0 << 16)
          | ((unsigned long long)(unsigned)i1 << 26)
          | ((unsigned long long)(unsigned)i2 << 36)
          | ((unsigned long long)(unsigned)i3 << 46);
    }
  }
  unsigned long long fm = __ballot(fpred);
  if (fm) {
    int leader = __ffsll(fm) - 1;
    int base = 0;
    if (lane == leader) base = atomicAdd(&counters[0], __popcll(fm));
    base = __shfl(base, leader);
    if (fpred) {
      int pos = __popcll(fm & ((1ull << lane) - 1ull));
      flaglist[base + pos] = pix;
    }
  }
}

// ---- K2a: exact fp64 check of <=4 candidates, one wave per pixel --------------
__global__ __launch_bounds__(256) void k2a_quad(
    const float* __restrict__ z, const float* __restrict__ cb,
    const unsigned long long* __restrict__ pairlist, const int* __restrict__ counters,
    int* __restrict__ idx_ws)
{
  const int lane = threadIdx.x & 63;
  const int wid  = (blockIdx.x << 2) + (threadIdx.x >> 6);
  const int nwav = gridDim.x << 2;
  const int nf   = counters[1];
  for (int e = wid; e < nf; e += nwav) {
    unsigned long long pk = pairlist[e];
    int pix = (int)(pk & 0xFFFFull);
    int c0 = (int)((pk >> 16) & 1023ull), c1 = (int)((pk >> 26) & 1023ull);
    int c2 = (int)((pk >> 36) & 1023ull), c3 = (int)((pk >> 46) & 1023ull);
    const float* zp = z + (size_t)(pix >> 12) * 512 * 4096 + (pix & 4095);
    double s0 = 0, s1 = 0, s2 = 0, s3 = 0;
    #pragma unroll
    for (int k = 0; k < 8; ++k) {
      int c = lane + (k << 6);
      double zv2 = 2.0 * (double)zp[(size_t)c * 4096];
      double a;
      a = (double)cb[(size_t)c0 * 512 + c]; s0 = fma(a, a - zv2, s0);
      a = (double)cb[(size_t)c1 * 512 + c]; s1 = fma(a, a - zv2, s1);
      a = (double)cb[(size_t)c2 * 512 + c]; s2 = fma(a, a - zv2, s2);
      a = (double)cb[(size_t)c3 * 512 + c]; s3 = fma(a, a - zv2, s3);
    }
    #pragma unroll
    for (int off = 32; off > 0; off >>= 1) {
      s0 += __shfl_xor(s0, off); s1 += __shfl_xor(s1, off);
      s2 += __shfl_xor(s2, off); s3 += __shfl_xor(s3, off);
    }
    double bv = s0; int bi = c0;
    if (s1 < bv || (s1 == bv && c1 < bi)) { bv = s1; bi = c1; }
    if (s2 < bv || (s2 == bv && c2 < bi)) { bv = s2; bi = c2; }
    if (s3 < bv || (s3 == bv && c3 < bi)) { bv = s3; bi = c3; }
    if (lane == 0) idx_ws[pix] = bi;
  }
}

// ---- K2b: exact fp64 full re-rank (rare: >=4 codes within margin) -------------
__global__ __launch_bounds__(256) void k2_rescan(
    const float* __restrict__ z, const float* __restrict__ cb,
    const int* __restrict__ flaglist, const int* __restrict__ counters,
    unsigned long long* __restrict__ packed_ws)
{
  __shared__ float zb[16][512];
  __shared__ unsigned long long best[16];
  __shared__ int pixl[16];
  const int t = threadIdx.x;
  const int nflag = counters[0];
  const int ntasks = ((nflag + 15) >> 4) << 2;
  for (int task = blockIdx.x; task < ntasks; task += gridDim.x) {
    const int g = task >> 2, q = task & 3;
    int rem = nflag - (g << 4);
    const int npx = rem < 16 ? rem : 16;
    if (t < 16) {
      best[t] = ~0ull;
      pixl[t] = (t < npx) ? flaglist[(g << 4) + t] : 0;
    }
    __syncthreads();
    for (int i = t; i < (npx << 9); i += 256) {
      int p = i >> 9, c = i & 511;
      int pix = pixl[p];
      zb[p][c] = z[((size_t)(pix >> 12) * 512 + c) * 4096 + (pix & 4095)];
    }
    __syncthreads();
    const int j = (q << 8) + t;
    const float* row = cb + (size_t)j * 512;
    double dot[16];
    #pragma unroll
    for (int p = 0; p < 16; ++p) dot[p] = 0.0;
    double cn = 0.0;
    for (int k = 0; k < 512; k += 4) {
      float4 cv = *(const float4*)(row + k);
      double c0 = cv.x, c1 = cv.y, c2 = cv.z, c3 = cv.w;
      cn = fma(c0, c0, cn); cn = fma(c1, c1, cn);
      cn = fma(c2, c2, cn); cn = fma(c3, c3, cn);
      #pragma unroll
      for (int p = 0; p < 16; ++p) {
        dot[p] = fma(c0, (double)zb[p][k + 0], dot[p]);
        dot[p] = fma(c1, (double)zb[p][k + 1], dot[p]);
        dot[p] = fma(c2, (double)zb[p][k + 2], dot[p]);
        dot[p] = fma(c3, (double)zb[p][k + 3], dot[p]);
      }
    }
    #pragma unroll
    for (int p = 0; p < 16; ++p) {
      if (p < npx) {
        double d = fma(-2.0, dot[p], cn);
        unsigned long long u = (unsigned long long)__double_as_longlong(d);
        u = (u >> 63) ? ~u : (u | 0x8000000000000000ull);
        unsigned long long pkk = (u & ~1023ull) | (unsigned long long)j;
        atomicMin(&best[p], pkk);
      }
    }
    __syncthreads();
    if (t < npx) atomicMin(&packed_ws[pixl[t]], best[t]);
    __syncthreads();
  }
}

// ---- K3: gather + transpose-write z_q (f32), idx (f32), loss ------------------
__global__ __launch_bounds__(256) void k3_out(
    const float* __restrict__ z, const float* __restrict__ cb,
    const int* __restrict__ idx_ws, const unsigned long long* __restrict__ packed_ws,
    float* __restrict__ out, float* __restrict__ loss_acc)
{
  extern __shared__ float rows[];         // [32][513]
  __shared__ int idxs[32];
  __shared__ float wsum[4];
  const int t = threadIdx.x;
  const int pix0 = blockIdx.x << 5;       // 32 px/block
  const int b = pix0 >> 12, hw0 = pix0 & 4095;
  if (t < 32) {
    int pix = pix0 + t;
    int v = idx_ws[pix];
    unsigned j = (v < 0) ? (unsigned)(packed_ws[pix] & 1023ull) : (unsigned)v;
    j &= 1023u;
    idxs[t] = (int)j;
    out[OUT_IDX + pix] = (float)j;
  }
  __syncthreads();
  for (int i = t; i < 32 * 128; i += 256) {
    int r = i >> 7, kq = (i & 127) << 2;
    float4 v = *(const float4*)(cb + (size_t)idxs[r] * 512 + kq);
    float* dst = rows + r * 513 + kq;
    dst[0] = v.x; dst[1] = v.y; dst[2] = v.z; dst[3] = v.w;
  }
  __syncthreads();
  const int pl = (t & 7) << 2;   // pixel quad {0,4,...,28}
  const int cg = t >> 3;         // 0..31
  float acc = 0.f;
  for (int c0 = 0; c0 < 512; c0 += 32) {
    int c = c0 + cg;
    size_t go = ((size_t)(b * 512 + c)) * 4096 + hw0 + pl;
    float4 zv = *(const float4*)(z + go);
    float q0 = rows[(pl + 0) * 513 + c], q1 = rows[(pl + 1) * 513 + c];
    float q2 = rows[(pl + 2) * 513 + c], q3 = rows[(pl + 3) * 513 + c];
    float d0 = q0 - zv.x, d1 = q1 - zv.y, d2 = q2 - zv.z, d3 = q3 - zv.w;
    acc = fmaf(d0, d0, acc); acc = fmaf(d1, d1, acc);
    acc = fmaf(d2, d2, acc); acc = fmaf(d3, d3, acc);
    float4 qv;
    qv.x = zv.x + d0; qv.y = zv.y + d1;    // mimic ref: zp + (z_q - zp)
    qv.z = zv.z + d2; qv.w = zv.w + d3;
    *reinterpret_cast<float4*>(out + go) = qv;
  }
  #pragma unroll
  for (int off = 32; off > 0; off >>= 1) acc += __shfl_down(acc, off);
  if ((t & 63) == 0) wsum[t >> 6] = acc;
  __syncthreads();
  if (t == 0) atomicAdd(loss_acc, wsum[0] + wsum[1] + wsum[2] + wsum[3]);
}

__global__ void k4_loss(const float* __restrict__ loss_acc, float* __restrict__ out)
{
  if (threadIdx.x == 0 && blockIdx.x == 0)
    out[OUT_LOSS] = loss_acc[0] * (1.25f / 33554432.f);
}

// ---- launch --------------------------------------------------------------------
extern "C" void kernel_launch(void* const* d_in, const int* in_sizes, int n_in,
                              void* d_out, int out_size, void* d_ws, size_t ws_size,
                              hipStream_t stream) {
  const float* z  = (const float*)d_in[0];
  const float* cb = (const float*)d_in[1];
  float* out = (float*)d_out;
  char* ws = (char*)d_ws;
  unsigned short*      cbT       = (unsigned short*)(ws);                 // 1 MB + 8 KB slack
  float*               cnp       = (float*)(ws + 1056768);                // 4 KB
  int*                 idx_ws    = (int*)(ws + 1060864);                  // 256 KB
  unsigned long long*  packed_ws = (unsigned long long*)(ws + 1323008);   // 512 KB
  int*                 flaglist  = (int*)(ws + 1847296);                  // 256 KB
  unsigned long long*  pairlist  = (unsigned long long*)(ws + 2109440);   // 512 KB
  int*                 counters  = (int*)(ws + 2633728);                  // [flag, pair]
  float*               loss_acc  = (float*)(ws + 2633736);

  (void)hipFuncSetAttribute((const void*)k3_out,
        hipFuncAttributeMaxDynamicSharedMemorySize, 65664);

  k0_prep<<<1024, 64, 0, stream>>>(cb, cbT, cnp, counters, loss_acc, idx_ws, packed_ws);
  k1_main<<<512, 256, 0, stream>>>(z, cbT, cnp, idx_ws, flaglist, pairlist, counters);
  k2a_quad<<<1024, 256, 0, stream>>>(z, cb, pairlist, counters, idx_ws);
  k2_rescan<<<256, 256, 0, stream>>>(z, cb, flaglist, counters, packed_ws);
  k3_out<<<2048, 256, 65664, stream>>>(z, cb, idx_ws, packed_ws, out, loss_acc);
  k4_loss<<<1, 1, 0, stream>>>(loss_acc, out);
}